// Round 6
// baseline (419.264 us; speedup 1.0000x reference)
//
#include <hip/hip_runtime.h>

// Problem constants: T=2048, B=2, E=1024, H=16, Dh=64, M = T*B = 4096
#define TT 2048
#define BB 2
#define EE 1024
#define MM 4096

typedef float f32x4 __attribute__((ext_vector_type(4)));
typedef short s16x8 __attribute__((ext_vector_type(8)));   // 8 bf16 (4 VGPRs)
typedef unsigned short u16x4 __attribute__((ext_vector_type(4)));

__device__ __forceinline__ unsigned short f2bf(float f) {
  unsigned int u = __builtin_bit_cast(unsigned int, f);
  u += 0x7fffu + ((u >> 16) & 1u);   // round-to-nearest-even
  return (unsigned short)(u >> 16);
}

__device__ __forceinline__ void mfma16(f32x4& d, s16x8 a, s16x8 b) {
  // D = A(16x32) * B(32x16) + D ; bf16 inputs, f32 acc. Builtin (NOT inline
  // asm): the compiler's hazard recognizer must see the MFMA to insert the
  // mandatory VALU->MFMA-SrcC / MFMA->VALU wait states.
  d = __builtin_amdgcn_mfma_f32_16x16x32_bf16(a, b, d, 0, 0, 0);
}

__device__ __forceinline__ void gload16(const void* g, void* l) {
  __builtin_amdgcn_global_load_lds((__attribute__((address_space(1))) void*)(void*)g,
                                   (__attribute__((address_space(3))) void*)l, 16, 0, 0);
}

// ---------------- prep kernels ----------------

__global__ void conv_x_kernel(const float* __restrict__ x, unsigned short* __restrict__ xb) {
  size_t i = ((size_t)blockIdx.x * blockDim.x + threadIdx.x) * 4;
  float4 v = *(const float4*)(x + i);
  u16x4 o = { f2bf(v.x), f2bf(v.y), f2bf(v.z), f2bf(v.w) };
  *(u16x4*)(xb + i) = o;
}

// Transpose+convert 5 weight matrices (stored [K][N] f32) into B^T bf16 ([N][K]).
__global__ void prep_w_kernel(const float* __restrict__ Wq, const float* __restrict__ Wk,
                              const float* __restrict__ Wv, const float* __restrict__ Wo,
                              const float* __restrict__ Wln,
                              unsigned short* __restrict__ Wqkvt,
                              unsigned short* __restrict__ Wot,
                              unsigned short* __restrict__ Wlnt) {
  int z = blockIdx.z;
  const float* W = (z == 0) ? Wq : (z == 1) ? Wk : (z == 2) ? Wv : (z == 3) ? Wo : Wln;
  unsigned short* dst = (z < 3) ? (Wqkvt + (size_t)z * EE * EE) : ((z == 3) ? Wot : Wlnt);
  __shared__ float tile[32][33];
  int k0 = blockIdx.x * 32, n0 = blockIdx.y * 32;
  int tx = threadIdx.x, ty = threadIdx.y;  // (32, 8)
#pragma unroll
  for (int i = 0; i < 4; ++i)
    tile[ty + i * 8][tx] = W[(size_t)(k0 + ty + i * 8) * EE + n0 + tx];
  __syncthreads();
#pragma unroll
  for (int i = 0; i < 4; ++i)
    dst[(size_t)(n0 + ty + i * 8) * EE + k0 + tx] = f2bf(tile[tx][ty + i * 8]);
}

// V part of qkv -> Vt[bh][d][t]  (bh = batch*16 + h)
__global__ void vtrans_kernel(const unsigned short* __restrict__ qkv,
                              unsigned short* __restrict__ Vt) {
  int bh = blockIdx.y; int batch = bh >> 4; int h = bh & 15;
  int t0 = blockIdx.x * 64;
  __shared__ unsigned short tile[64][72];
  int l = threadIdx.x & 63, c = threadIdx.x >> 6;  // c = 0..3
#pragma unroll
  for (int rr = 0; rr < 16; ++rr) {
    int t = c * 16 + rr;
    tile[t][l] = qkv[(size_t)((t0 + t) * BB + batch) * 3072 + 2048 + h * 64 + l];
  }
  __syncthreads();
#pragma unroll
  for (int dd = 0; dd < 16; ++dd) {
    int d = c * 16 + dd;
    Vt[((size_t)bh * 64 + d) * TT + t0 + l] = tile[l][d];
  }
}

// ---------------- GEMM: C[M][N] = A[M][K] @ Bt[N][K]^T (+ epilogue) ----------------
// 128x128 tile, BK=64, 4 waves (2x2). XOR swizzle on staging source + ds_read.
// EPI: 0 = +bias(q|k|v concat) -> bf16 qkv[M][3072]
//      1 = +bias +resid(f32)   -> bf16 y[M][1024]
//      2 = +bias               -> f32 out[M][1024]   (d_out is f32: R2/R4 decode forensics)
template <int EPI>
__global__ __launch_bounds__(256) void gemm_bt(
    const unsigned short* __restrict__ A, const unsigned short* __restrict__ Bt,
    const float* __restrict__ b0, const float* __restrict__ b1, const float* __restrict__ b2,
    const float* __restrict__ resid, unsigned short* __restrict__ outb,
    float* __restrict__ outf) {
  constexpr int K = 1024;
  constexpr int OS = (EPI == 0) ? 3072 : 1024;
  __shared__ __align__(16) unsigned short As[128 * 64];
  __shared__ __align__(16) unsigned short Bs[128 * 64];
  const int m0 = blockIdx.y * 128, n0 = blockIdx.x * 128;
  const int tid = threadIdx.x;
  const int lane = tid & 63, w = tid >> 6;
  const int wm = w >> 1, wn = w & 1;
  const int g = lane >> 4, qi = lane & 15;
  const int srow = tid >> 3;   // 0..31 per staging issue
  const int sslot = tid & 7;   // 16B slot within a 128B row

  f32x4 acc[4][4] = {};

  for (int k0 = 0; k0 < K; k0 += 64) {
#pragma unroll
    for (int i = 0; i < 4; ++i) {
      int row = i * 32 + srow;
      int slot = sslot ^ (row & 7);  // inverse-swizzled source, linear LDS dest
      gload16(A + (size_t)(m0 + row) * K + k0 + slot * 8, &As[i * 2048 + w * 512]);
      gload16(Bt + (size_t)(n0 + row) * K + k0 + slot * 8, &Bs[i * 2048 + w * 512]);
    }
    __syncthreads();
#pragma unroll
    for (int ks = 0; ks < 2; ++ks) {
      s16x8 af[4], bfr[4];
#pragma unroll
      for (int i = 0; i < 4; ++i) {
        int ar = wm * 64 + i * 16 + qi;
        af[i] = *(const s16x8*)(As + ar * 64 + (((ks * 4 + g) ^ (ar & 7)) * 8));
        int br = wn * 64 + i * 16 + qi;
        bfr[i] = *(const s16x8*)(Bs + br * 64 + (((ks * 4 + g) ^ (br & 7)) * 8));
      }
#pragma unroll
      for (int i = 0; i < 4; ++i)
#pragma unroll
        for (int j = 0; j < 4; ++j) mfma16(acc[i][j], af[i], bfr[j]);
    }
    __syncthreads();
  }

#pragma unroll
  for (int i = 0; i < 4; ++i) {
    int row0 = m0 + wm * 64 + i * 16 + g * 4;
#pragma unroll
    for (int j = 0; j < 4; ++j) {
      int col = n0 + wn * 64 + j * 16 + qi;
#pragma unroll
      for (int r = 0; r < 4; ++r) {
        int row = row0 + r;
        float v = acc[i][j][r];
        if (EPI == 0) {
          float b = (col < 1024) ? b0[col] : (col < 2048) ? b1[col - 1024] : b2[col - 2048];
          outb[(size_t)row * OS + col] = f2bf(v + b);
        } else if (EPI == 1) {
          v += b0[col] + resid[(size_t)row * OS + col];
          outb[(size_t)row * OS + col] = f2bf(v);
        } else {
          outf[(size_t)row * OS + col] = v + b0[col];
        }
      }
    }
  }
}

// ---------------- attention ----------------
// One wave per (16 q-rows, bh). Swapped QK^T / swapped PV; strictly causal
// (j < i) with softmax sink (m0 = 0, l0 = 1).
__global__ __launch_bounds__(64) void attn_kernel(const unsigned short* __restrict__ qkv,
                                                  const unsigned short* __restrict__ Vt,
                                                  unsigned short* __restrict__ attnb) {
  const int bh = blockIdx.y; const int batch = bh >> 4; const int h = bh & 15;
  const int q0 = blockIdx.x * 16;
  const int lane = threadIdx.x & 63;
  const int g = lane >> 4, qi = lane & 15;

  __shared__ __align__(16) unsigned short P[16 * 40];  // [qi][j], pad 32->40

  const unsigned short* qbase = qkv + h * 64;
  const unsigned short* kbase = qkv + 1024 + h * 64;
  const unsigned short* vtb = Vt + (size_t)bh * 64 * TT;

  const size_t qrow = (size_t)((q0 + qi) * BB + batch) * 3072;
  const s16x8 qf0 = *(const s16x8*)(qbase + qrow + g * 8);        // d 0..31
  const s16x8 qf1 = *(const s16x8*)(qbase + qrow + 32 + g * 8);   // d 32..63

  float m_run = 0.f, l_run = 1.f;  // sink: zero logit, zero value
  f32x4 o[4] = {};                 // O^T frags: d = mt*16 + g*4 + r, col qi

  const int iglob = q0 + qi;
  for (int j0 = 0; j0 < q0 + 16; j0 += 32) {
    f32x4 s0 = {}, s1 = {};
    {
      size_t kr0 = (size_t)((j0 + qi) * BB + batch) * 3072;
      size_t kr1 = (size_t)((j0 + 16 + qi) * BB + batch) * 3072;
      s16x8 ka = *(const s16x8*)(kbase + kr0 + g * 8);
      s16x8 kb = *(const s16x8*)(kbase + kr0 + 32 + g * 8);
      s16x8 kc = *(const s16x8*)(kbase + kr1 + g * 8);
      s16x8 kd = *(const s16x8*)(kbase + kr1 + 32 + g * 8);
      mfma16(s0, ka, qf0); mfma16(s0, kb, qf1);   // S^T rows j0..j0+15
      mfma16(s1, kc, qf0); mfma16(s1, kd, qf1);   // S^T rows j0+16..j0+31
    }
    float lg[8];
#pragma unroll
    for (int r = 0; r < 4; ++r) {
      int ja = j0 + g * 4 + r, jb = j0 + 16 + g * 4 + r;
      lg[r]     = (ja < iglob) ? 0.125f * s0[r] : -1e30f;
      lg[4 + r] = (jb < iglob) ? 0.125f * s1[r] : -1e30f;
    }
    float tmax = lg[0];
#pragma unroll
    for (int r = 1; r < 8; ++r) tmax = fmaxf(tmax, lg[r]);
    tmax = fmaxf(tmax, __shfl_xor(tmax, 16));
    tmax = fmaxf(tmax, __shfl_xor(tmax, 32));
    float m_new = fmaxf(m_run, tmax);
    float fac = __expf(m_run - m_new);
    float p[8]; float rs = 0.f;
#pragma unroll
    for (int r = 0; r < 8; ++r) { p[r] = __expf(lg[r] - m_new); rs += p[r]; }
    rs += __shfl_xor(rs, 16);
    rs += __shfl_xor(rs, 32);
    l_run = l_run * fac + rs;
    m_run = m_new;
#pragma unroll
    for (int mt = 0; mt < 4; ++mt)
#pragma unroll
      for (int r = 0; r < 4; ++r) o[mt][r] *= fac;

    __syncthreads();  // WAR: previous tile's P reads complete
    *(unsigned int*)&P[qi * 40 + g * 4]          = (unsigned int)f2bf(p[0]) | ((unsigned int)f2bf(p[1]) << 16);
    *(unsigned int*)&P[qi * 40 + g * 4 + 2]      = (unsigned int)f2bf(p[2]) | ((unsigned int)f2bf(p[3]) << 16);
    *(unsigned int*)&P[qi * 40 + 16 + g * 4]     = (unsigned int)f2bf(p[4]) | ((unsigned int)f2bf(p[5]) << 16);
    *(unsigned int*)&P[qi * 40 + 16 + g * 4 + 2] = (unsigned int)f2bf(p[6]) | ((unsigned int)f2bf(p[7]) << 16);
    __syncthreads();  // RAW: P visible before fragment read
    s16x8 pf = *(const s16x8*)&P[qi * 40 + g * 8];

#pragma unroll
    for (int mt = 0; mt < 4; ++mt) {
      s16x8 vf = *(const s16x8*)(vtb + (size_t)(mt * 16 + qi) * TT + j0 + g * 8);
      mfma16(o[mt], vf, pf);  // O^T[d][qi] += Vt * P^T
    }
  }

  float inv = 1.f / l_run;
  size_t orow = (size_t)((q0 + qi) * BB + batch) * 1024 + h * 64;
#pragma unroll
  for (int mt = 0; mt < 4; ++mt) {
    u16x4 ov = { f2bf(o[mt][0] * inv), f2bf(o[mt][1] * inv),
                 f2bf(o[mt][2] * inv), f2bf(o[mt][3] * inv) };
    *(u16x4*)(attnb + orow + mt * 16 + g * 4) = ov;
  }
}

// ---------------- launcher ----------------

extern "C" void kernel_launch(void* const* d_in, const int* in_sizes, int n_in,
                              void* d_out, int out_size, void* d_ws, size_t ws_size,
                              hipStream_t stream) {
  (void)in_sizes; (void)n_in; (void)out_size; (void)ws_size;
  const float* x   = (const float*)d_in[0];
  const float* Wq  = (const float*)d_in[1];
  const float* bq  = (const float*)d_in[2];
  const float* Wk  = (const float*)d_in[3];
  const float* bk  = (const float*)d_in[4];
  const float* Wv  = (const float*)d_in[5];
  const float* bv  = (const float*)d_in[6];
  const float* Wo  = (const float*)d_in[7];
  const float* bo  = (const float*)d_in[8];
  const float* Wln = (const float*)d_in[9];
  const float* bln = (const float*)d_in[10];
  float* out = (float*)d_out;   // harness output buffer is f32 (R2/R4 forensics)

  char* ws = (char*)d_ws;
  unsigned short* xb    = (unsigned short*)(ws);                        //  8MB [4096][1024]
  unsigned short* qkv   = (unsigned short*)(ws + ((size_t)8 << 20));    // 24MB [4096][3072]
  unsigned short* Wqkvt = (unsigned short*)(ws + ((size_t)32 << 20));   //  6MB [3072][1024]
  unsigned short* Wot   = (unsigned short*)(ws + ((size_t)38 << 20));   //  2MB [1024][1024]
  unsigned short* Wlnt  = (unsigned short*)(ws + ((size_t)40 << 20));   //  2MB [1024][1024]
  unsigned short* Vt    = (unsigned short*)(ws + ((size_t)42 << 20));   //  8MB [32*64][2048]
  unsigned short* attnb = (unsigned short*)(ws + ((size_t)50 << 20));   //  8MB [4096][1024]
  unsigned short* yb    = xb;  // xb dead after QKV GEMM; reuse for y

  conv_x_kernel<<<4096, 256, 0, stream>>>(x, xb);
  prep_w_kernel<<<dim3(32, 32, 5), dim3(32, 8), 0, stream>>>(Wq, Wk, Wv, Wo, Wln,
                                                             Wqkvt, Wot, Wlnt);
  // qkv = x @ [Wq|Wk|Wv] + [bq|bk|bv]
  gemm_bt<0><<<dim3(24, 32), 256, 0, stream>>>(xb, Wqkvt, bq, bk, bv, nullptr, qkv, nullptr);
  vtrans_kernel<<<dim3(32, 32), 256, 0, stream>>>(qkv, Vt);
  attn_kernel<<<dim3(128, 32), 64, 0, stream>>>(qkv, Vt, attnb);
  // y = attn @ Wo + bo + x
  gemm_bt<1><<<dim3(8, 32), 256, 0, stream>>>(attnb, Wot, bo, nullptr, nullptr, x, yb, nullptr);
  // out = y @ Wln + bln  (f32 out)
  gemm_bt<2><<<dim3(8, 32), 256, 0, stream>>>(yb, Wlnt, bln, nullptr, nullptr, nullptr, nullptr, out);
}

// Round 7
// 326.478 us; speedup vs baseline: 1.2842x; 1.2842x over previous
//
#include <hip/hip_runtime.h>

// Problem constants: T=2048, B=2, E=1024, H=16, Dh=64, M = T*B = 4096
#define TT 2048
#define BB 2
#define EE 1024
#define MM 4096

typedef float f32x4 __attribute__((ext_vector_type(4)));
typedef short s16x8 __attribute__((ext_vector_type(8)));   // 8 bf16 (4 VGPRs)
typedef unsigned short u16x4 __attribute__((ext_vector_type(4)));
typedef unsigned int u32x4 __attribute__((ext_vector_type(4)));

__device__ __forceinline__ unsigned short f2bf(float f) {
  unsigned int u = __builtin_bit_cast(unsigned int, f);
  u += 0x7fffu + ((u >> 16) & 1u);   // round-to-nearest-even
  return (unsigned short)(u >> 16);
}

__device__ __forceinline__ void mfma16(f32x4& d, s16x8 a, s16x8 b) {
  // Builtin (NOT inline asm): hazard recognizer must see the MFMA to insert
  // mandatory VALU->MFMA-SrcC / MFMA->VALU wait states (R4->R6 lesson).
  d = __builtin_amdgcn_mfma_f32_16x16x32_bf16(a, b, d, 0, 0, 0);
}

__device__ __forceinline__ void gload16(const void* g, void* l) {
  __builtin_amdgcn_global_load_lds((__attribute__((address_space(1))) void*)(void*)g,
                                   (__attribute__((address_space(3))) void*)l, 16, 0, 0);
}

// ---------------- prep kernels ----------------

__global__ void conv_x_kernel(const float* __restrict__ x, unsigned short* __restrict__ xb) {
  size_t i = ((size_t)blockIdx.x * blockDim.x + threadIdx.x) * 4;
  float4 v = *(const float4*)(x + i);
  u16x4 o = { f2bf(v.x), f2bf(v.y), f2bf(v.z), f2bf(v.w) };
  *(u16x4*)(xb + i) = o;
}

// Transpose+convert 5 weight matrices (stored [K][N] f32) into B^T bf16 ([N][K]).
__global__ void prep_w_kernel(const float* __restrict__ Wq, const float* __restrict__ Wk,
                              const float* __restrict__ Wv, const float* __restrict__ Wo,
                              const float* __restrict__ Wln,
                              unsigned short* __restrict__ Wqkvt,
                              unsigned short* __restrict__ Wot,
                              unsigned short* __restrict__ Wlnt) {
  int z = blockIdx.z;
  const float* W = (z == 0) ? Wq : (z == 1) ? Wk : (z == 2) ? Wv : (z == 3) ? Wo : Wln;
  unsigned short* dst = (z < 3) ? (Wqkvt + (size_t)z * EE * EE) : ((z == 3) ? Wot : Wlnt);
  __shared__ float tile[32][33];
  int k0 = blockIdx.x * 32, n0 = blockIdx.y * 32;
  int tx = threadIdx.x, ty = threadIdx.y;  // (32, 8)
#pragma unroll
  for (int i = 0; i < 4; ++i)
    tile[ty + i * 8][tx] = W[(size_t)(k0 + ty + i * 8) * EE + n0 + tx];
  __syncthreads();
#pragma unroll
  for (int i = 0; i < 4; ++i)
    dst[(size_t)(n0 + ty + i * 8) * EE + k0 + tx] = f2bf(tile[tx][ty + i * 8]);
}

// V part of qkv -> Vt[bh][d][t]  (bh = batch*16 + h)
__global__ void vtrans_kernel(const unsigned short* __restrict__ qkv,
                              unsigned short* __restrict__ Vt) {
  int bh = blockIdx.y; int batch = bh >> 4; int h = bh & 15;
  int t0 = blockIdx.x * 64;
  __shared__ unsigned short tile[64][72];
  int l = threadIdx.x & 63, c = threadIdx.x >> 6;  // c = 0..3
#pragma unroll
  for (int rr = 0; rr < 16; ++rr) {
    int t = c * 16 + rr;
    tile[t][l] = qkv[(size_t)((t0 + t) * BB + batch) * 3072 + 2048 + h * 64 + l];
  }
  __syncthreads();
#pragma unroll
  for (int dd = 0; dd < 16; ++dd) {
    int d = c * 16 + dd;
    Vt[((size_t)bh * 64 + d) * TT + t0 + l] = tile[l][d];
  }
}

// ---------------- GEMM: C[M][N] = A[M][K] @ Bt[N][K]^T (+ epilogue) ----------------
// 128x128 tile, BK=64, 4 waves (2x2). XOR swizzle on staging source + ds_read.
// EPI: 0 = +bias(q|k|v concat) -> bf16 qkv[M][3072]
//      1 = +bias +resid(f32)   -> bf16 y[M][1024]
//      2 = +bias               -> f32 out[M][1024]
template <int EPI>
__global__ __launch_bounds__(256) void gemm_bt(
    const unsigned short* __restrict__ A, const unsigned short* __restrict__ Bt,
    const float* __restrict__ b0, const float* __restrict__ b1, const float* __restrict__ b2,
    const float* __restrict__ resid, unsigned short* __restrict__ outb,
    float* __restrict__ outf) {
  constexpr int K = 1024;
  constexpr int OS = (EPI == 0) ? 3072 : 1024;
  __shared__ __align__(16) unsigned short As[128 * 64];
  __shared__ __align__(16) unsigned short Bs[128 * 64];
  const int m0 = blockIdx.y * 128, n0 = blockIdx.x * 128;
  const int tid = threadIdx.x;
  const int lane = tid & 63, w = tid >> 6;
  const int wm = w >> 1, wn = w & 1;
  const int g = lane >> 4, qi = lane & 15;
  const int srow = tid >> 3;   // 0..31 per staging issue
  const int sslot = tid & 7;   // 16B slot within a 128B row

  f32x4 acc[4][4] = {};

  for (int k0 = 0; k0 < K; k0 += 64) {
#pragma unroll
    for (int i = 0; i < 4; ++i) {
      int row = i * 32 + srow;
      int slot = sslot ^ (row & 7);  // inverse-swizzled source, linear LDS dest
      gload16(A + (size_t)(m0 + row) * K + k0 + slot * 8, &As[i * 2048 + w * 512]);
      gload16(Bt + (size_t)(n0 + row) * K + k0 + slot * 8, &Bs[i * 2048 + w * 512]);
    }
    __syncthreads();
#pragma unroll
    for (int ks = 0; ks < 2; ++ks) {
      s16x8 af[4], bfr[4];
#pragma unroll
      for (int i = 0; i < 4; ++i) {
        int ar = wm * 64 + i * 16 + qi;
        af[i] = *(const s16x8*)(As + ar * 64 + (((ks * 4 + g) ^ (ar & 7)) * 8));
        int br = wn * 64 + i * 16 + qi;
        bfr[i] = *(const s16x8*)(Bs + br * 64 + (((ks * 4 + g) ^ (br & 7)) * 8));
      }
#pragma unroll
      for (int i = 0; i < 4; ++i)
#pragma unroll
        for (int j = 0; j < 4; ++j) mfma16(acc[i][j], af[i], bfr[j]);
    }
    __syncthreads();
  }

#pragma unroll
  for (int i = 0; i < 4; ++i) {
    int row0 = m0 + wm * 64 + i * 16 + g * 4;
#pragma unroll
    for (int j = 0; j < 4; ++j) {
      int col = n0 + wn * 64 + j * 16 + qi;
#pragma unroll
      for (int r = 0; r < 4; ++r) {
        int row = row0 + r;
        float v = acc[i][j][r];
        if (EPI == 0) {
          float b = (col < 1024) ? b0[col] : (col < 2048) ? b1[col - 1024] : b2[col - 2048];
          outb[(size_t)row * OS + col] = f2bf(v + b);
        } else if (EPI == 1) {
          v += b0[col] + resid[(size_t)row * OS + col];
          outb[(size_t)row * OS + col] = f2bf(v);
        } else {
          outf[(size_t)row * OS + col] = v + b0[col];
        }
      }
    }
  }
}

// ---------------- attention ----------------
// One wave per block; block handles TWO mirror-paired q-tiles (p, 127-p) so
// every block does exactly 65 j-iterations (perfect causal load balance).
// Zero barriers / zero LDS: K(j+1) and V(j) register-prefetched; the P
// transpose (C-frag rows g*4+r -> A-frag cols g*8+i) done with 8 __shfl
// (register-level, compiler-visible deps -> loads stay in flight).
__global__ __launch_bounds__(64) void attn_kernel(const unsigned short* __restrict__ qkv,
                                                  const unsigned short* __restrict__ Vt,
                                                  unsigned short* __restrict__ attnb) {
  const int bh = blockIdx.y; const int batch = bh >> 4; const int h = bh & 15;
  const int lane = threadIdx.x & 63;
  const int g = lane >> 4, qi = lane & 15;

  const unsigned short* qbase = qkv + h * 64;
  const unsigned short* kbase = qkv + 1024 + h * 64;
  const unsigned short* vtb = Vt + (size_t)bh * 64 * TT;

#pragma unroll 1
  for (int half = 0; half < 2; ++half) {
    const int q0 = (half ? (127 - (int)blockIdx.x) : (int)blockIdx.x) * 16;
    const size_t qrow = (size_t)((q0 + qi) * BB + batch) * 3072;
    const s16x8 qf0 = *(const s16x8*)(qbase + qrow + g * 8);        // d 0..31
    const s16x8 qf1 = *(const s16x8*)(qbase + qrow + 32 + g * 8);   // d 32..63

    float m_run = 0.f, l_run = 1.f;  // sink: zero logit, zero value
    f32x4 o[4] = {};                 // O^T frags: d = mt*16 + g*4 + r, col qi
    const int iglob = q0 + qi;
    const int jend = q0 + 16;

    // prefetch K tile for j0 = 0
    s16x8 ka, kb, kc, kd;
    {
      size_t kr0 = (size_t)(qi * BB + batch) * 3072;
      size_t kr1 = (size_t)((16 + qi) * BB + batch) * 3072;
      ka = *(const s16x8*)(kbase + kr0 + g * 8);
      kb = *(const s16x8*)(kbase + kr0 + 32 + g * 8);
      kc = *(const s16x8*)(kbase + kr1 + g * 8);
      kd = *(const s16x8*)(kbase + kr1 + 32 + g * 8);
    }

#pragma unroll 1
    for (int j0 = 0; j0 < jend; j0 += 32) {
      // V loads for current tile — latency covered by QK^T + softmax below
      s16x8 vf0 = *(const s16x8*)(vtb + (size_t)(qi)*TT + j0 + g * 8);
      s16x8 vf1 = *(const s16x8*)(vtb + (size_t)(16 + qi) * TT + j0 + g * 8);
      s16x8 vf2 = *(const s16x8*)(vtb + (size_t)(32 + qi) * TT + j0 + g * 8);
      s16x8 vf3 = *(const s16x8*)(vtb + (size_t)(48 + qi) * TT + j0 + g * 8);
      // prefetch next K tile — latency covered by the rest of this iteration
      const int jn = (j0 + 32 < jend) ? j0 + 32 : 0;
      s16x8 na, nb, nc, nd;
      {
        size_t kr0 = (size_t)((jn + qi) * BB + batch) * 3072;
        size_t kr1 = (size_t)((jn + 16 + qi) * BB + batch) * 3072;
        na = *(const s16x8*)(kbase + kr0 + g * 8);
        nb = *(const s16x8*)(kbase + kr0 + 32 + g * 8);
        nc = *(const s16x8*)(kbase + kr1 + g * 8);
        nd = *(const s16x8*)(kbase + kr1 + 32 + g * 8);
      }

      f32x4 s0 = {}, s1 = {};
      mfma16(s0, ka, qf0); mfma16(s0, kb, qf1);   // S^T rows j0..j0+15
      mfma16(s1, kc, qf0); mfma16(s1, kd, qf1);   // S^T rows j0+16..j0+31

      float lg[8];
#pragma unroll
      for (int r = 0; r < 4; ++r) {
        int ja = j0 + g * 4 + r, jb = j0 + 16 + g * 4 + r;
        lg[r]     = (ja < iglob) ? 0.125f * s0[r] : -1e30f;
        lg[4 + r] = (jb < iglob) ? 0.125f * s1[r] : -1e30f;
      }
      float tmax = lg[0];
#pragma unroll
      for (int r = 1; r < 8; ++r) tmax = fmaxf(tmax, lg[r]);
      tmax = fmaxf(tmax, __shfl_xor(tmax, 16));
      tmax = fmaxf(tmax, __shfl_xor(tmax, 32));
      float m_new = fmaxf(m_run, tmax);
      float fac = __expf(m_run - m_new);
      float p[8]; float rs = 0.f;
#pragma unroll
      for (int r = 0; r < 8; ++r) { p[r] = __expf(lg[r] - m_new); rs += p[r]; }
      rs += __shfl_xor(rs, 16);
      rs += __shfl_xor(rs, 32);
      l_run = l_run * fac + rs;
      m_run = m_new;
#pragma unroll
      for (int mt = 0; mt < 4; ++mt)
#pragma unroll
        for (int r = 0; r < 4; ++r) o[mt][r] *= fac;

      // in-register P transpose: lane (g,qi) holds P[q=qi][j=g*4+r, 16+g*4+r];
      // PV A-frag needs P[q=qi][j=g*8..g*8+7]. 8 shfl + selects, no LDS.
      unsigned w0 = (unsigned)f2bf(p[0]) | ((unsigned)f2bf(p[1]) << 16);
      unsigned w1 = (unsigned)f2bf(p[2]) | ((unsigned)f2bf(p[3]) << 16);
      unsigned w2 = (unsigned)f2bf(p[4]) | ((unsigned)f2bf(p[5]) << 16);
      unsigned w3 = (unsigned)f2bf(p[6]) | ((unsigned)f2bf(p[7]) << 16);
      const int srcA = ((g & 1) << 5) + qi;   // lane of group gA = (g&1)*2
      const int srcB = srcA + 16;             // lane of group gA+1
      unsigned a0 = (unsigned)__shfl((int)w0, srcA);
      unsigned a1 = (unsigned)__shfl((int)w1, srcA);
      unsigned a2 = (unsigned)__shfl((int)w2, srcA);
      unsigned a3 = (unsigned)__shfl((int)w3, srcA);
      unsigned b0 = (unsigned)__shfl((int)w0, srcB);
      unsigned b1 = (unsigned)__shfl((int)w1, srcB);
      unsigned b2 = (unsigned)__shfl((int)w2, srcB);
      unsigned b3 = (unsigned)__shfl((int)w3, srcB);
      u32x4 pw;
      pw.x = (g < 2) ? a0 : a2;
      pw.y = (g < 2) ? a1 : a3;
      pw.z = (g < 2) ? b0 : b2;
      pw.w = (g < 2) ? b1 : b3;
      s16x8 pf = __builtin_bit_cast(s16x8, pw);

      mfma16(o[0], vf0, pf);   // O^T[d][qi] += Vt * P^T
      mfma16(o[1], vf1, pf);
      mfma16(o[2], vf2, pf);
      mfma16(o[3], vf3, pf);

      ka = na; kb = nb; kc = nc; kd = nd;
    }

    float inv = 1.f / l_run;
    size_t orow = (size_t)((q0 + qi) * BB + batch) * 1024 + h * 64;
#pragma unroll
    for (int mt = 0; mt < 4; ++mt) {
      u16x4 ov = { f2bf(o[mt][0] * inv), f2bf(o[mt][1] * inv),
                   f2bf(o[mt][2] * inv), f2bf(o[mt][3] * inv) };
      *(u16x4*)(attnb + orow + mt * 16 + g * 4) = ov;
    }
  }
}

// ---------------- launcher ----------------

extern "C" void kernel_launch(void* const* d_in, const int* in_sizes, int n_in,
                              void* d_out, int out_size, void* d_ws, size_t ws_size,
                              hipStream_t stream) {
  (void)in_sizes; (void)n_in; (void)out_size; (void)ws_size;
  const float* x   = (const float*)d_in[0];
  const float* Wq  = (const float*)d_in[1];
  const float* bq  = (const float*)d_in[2];
  const float* Wk  = (const float*)d_in[3];
  const float* bk  = (const float*)d_in[4];
  const float* Wv  = (const float*)d_in[5];
  const float* bv  = (const float*)d_in[6];
  const float* Wo  = (const float*)d_in[7];
  const float* bo  = (const float*)d_in[8];
  const float* Wln = (const float*)d_in[9];
  const float* bln = (const float*)d_in[10];
  float* out = (float*)d_out;   // harness output buffer is f32

  char* ws = (char*)d_ws;
  unsigned short* xb    = (unsigned short*)(ws);                        //  8MB [4096][1024]
  unsigned short* qkv   = (unsigned short*)(ws + ((size_t)8 << 20));    // 24MB [4096][3072]
  unsigned short* Wqkvt = (unsigned short*)(ws + ((size_t)32 << 20));   //  6MB [3072][1024]
  unsigned short* Wot   = (unsigned short*)(ws + ((size_t)38 << 20));   //  2MB [1024][1024]
  unsigned short* Wlnt  = (unsigned short*)(ws + ((size_t)40 << 20));   //  2MB [1024][1024]
  unsigned short* Vt    = (unsigned short*)(ws + ((size_t)42 << 20));   //  8MB [32*64][2048]
  unsigned short* attnb = (unsigned short*)(ws + ((size_t)50 << 20));   //  8MB [4096][1024]
  unsigned short* yb    = xb;  // xb dead after QKV GEMM; reuse for y

  conv_x_kernel<<<4096, 256, 0, stream>>>(x, xb);
  prep_w_kernel<<<dim3(32, 32, 5), dim3(32, 8), 0, stream>>>(Wq, Wk, Wv, Wo, Wln,
                                                             Wqkvt, Wot, Wlnt);
  // qkv = x @ [Wq|Wk|Wv] + [bq|bk|bv]
  gemm_bt<0><<<dim3(24, 32), 256, 0, stream>>>(xb, Wqkvt, bq, bk, bv, nullptr, qkv, nullptr);
  vtrans_kernel<<<dim3(32, 32), 256, 0, stream>>>(qkv, Vt);
  attn_kernel<<<dim3(64, 32), 64, 0, stream>>>(qkv, Vt, attnb);
  // y = attn @ Wo + bo + x
  gemm_bt<1><<<dim3(8, 32), 256, 0, stream>>>(attnb, Wot, bo, nullptr, nullptr, x, yb, nullptr);
  // out = y @ Wln + bln  (f32 out)
  gemm_bt<2><<<dim3(8, 32), 256, 0, stream>>>(yb, Wlnt, bln, nullptr, nullptr, nullptr, nullptr, out);
}